// Round 17
// baseline (1917.786 us; speedup 1.0000x reference)
//
#include <hip/hip_runtime.h>
#include <stdint.h>

// ---------------------------------------------------------------------------
// GRU encoder (B=128,T=512,D=512,H=512,L=256), MI355X gfx950.
//
// R22 = R21 (fused persistent gru+ig, PASSED 1899us) with two refinements:
//   1) cvt passes dropped: producers stage fp32->bf16 INLINE (R20-proven
//      legacy K-loop). Producers have 4x slack (ig ~400us vs gru 1600us),
//      so the extra VALU is free; deletes ~50-70us of serial cvt+launch.
//   2) ALL 256 blocks produce quarter-0 first (6 tiles each, tile=bid+256k),
//      then blocks 0..63 run the gru body, 64..255 continue quarters 1..3.
//      Quarter-0 latency 8->6 tiles; gru's t=0 poll mostly falls through.
// Protocols unchanged from R21 (all proven):
//   - gru body = R16 verbatim (sentinel ring, prefetch-as-poll, strided
//     fill, 2 barriers) + per-quarter qcnt wait at t%128==0.
//   - ig tile signal: sc0sc1 stores -> per-thread vmcnt(0) -> syncthreads
//     -> tid0 atomicAdd(qcnt+qq,1); gru polls qcnt[t>>7] >= 1536.
//   - IG consumer loads plain (deterministic pipeline => stale lines are
//     bit-identical; first touch fetches from the coherence point).
// Deadlock-free: grid=256 <= 256 CUs, 70KB LDS, <=256 VGPR -> 1 block/CU,
// all resident; quarter-0 production is unconditional (no waits before it);
// producers never wait on gru.
// ---------------------------------------------------------------------------

typedef short short8 __attribute__((ext_vector_type(8)));
typedef float f32x4 __attribute__((ext_vector_type(4)));
typedef int int4v __attribute__((ext_vector_type(4)));

#define NB 128
#define NT 512
#define ND 512
#define NH 512
#define NG 1536   // 3H
#define HSLOT (NB * NH)  // shorts per h ring slot (128 KB)

__device__ __forceinline__ unsigned short f2bf(float f) {
  union { float f; unsigned u; } v; v.f = f;
  unsigned r = v.u + 0x7fffu + ((v.u >> 16) & 1u);  // RNE
  return (unsigned short)(r >> 16);
}
__device__ __forceinline__ float bf2f(unsigned short u) {
  union { unsigned u; float f; } v; v.u = ((unsigned)u) << 16; return v.f;
}
__device__ __forceinline__ float sigmoid_f(float x) {
  float e = __builtin_amdgcn_exp2f(-1.4426950408889634f * x);
  return __builtin_amdgcn_rcpf(1.0f + e);
}
__device__ __forceinline__ float tanh_f(float x) {
  float e = __builtin_amdgcn_exp2f(2.8853900817779268f * x);
  return 1.0f - 2.0f * __builtin_amdgcn_rcpf(1.0f + e);
}
__device__ __forceinline__ short8 pack8(float4 a, float4 b) {
  short8 s;
  s[0] = (short)f2bf(a.x); s[1] = (short)f2bf(a.y);
  s[2] = (short)f2bf(a.z); s[3] = (short)f2bf(a.w);
  s[4] = (short)f2bf(b.x); s[5] = (short)f2bf(b.y);
  s[6] = (short)f2bf(b.z); s[7] = (short)f2bf(b.w);
  return s;
}

// issue 4 coherent 16B loads, NO wait (prefetch path)
__device__ __forceinline__ void issue4(const unsigned short* r0,
                                       const unsigned short* r1,
                                       const unsigned short* r2,
                                       const unsigned short* r3,
                                       int4v (&v)[4]) {
  asm volatile(
      "global_load_dwordx4 %0, %4, off sc0 sc1\n\t"
      "global_load_dwordx4 %1, %5, off sc0 sc1\n\t"
      "global_load_dwordx4 %2, %6, off sc0 sc1\n\t"
      "global_load_dwordx4 %3, %7, off sc0 sc1"
      : "=&v"(v[0]), "=&v"(v[1]), "=&v"(v[2]), "=&v"(v[3])
      : "v"(r0), "v"(r1), "v"(r2), "v"(r3) : "memory");
}

// drain all vmem; v passed through so later uses are data-ordered after
// the wait (robust against hoisting, rule #18).
__device__ __forceinline__ void wait4(int4v (&v)[4]) {
  asm volatile("s_waitcnt vmcnt(0)"
               : "+v"(v[0]), "+v"(v[1]), "+v"(v[2]), "+v"(v[3]) :: "memory");
}

__device__ __forceinline__ int4v load16_s(const unsigned short* p) {
  int4v v;
  asm volatile("global_load_dwordx4 %0, %1, off sc0 sc1\n\t"
               "s_waitcnt vmcnt(0)"
               : "=v"(v) : "v"(p) : "memory");
  return v;
}

// coalesced coherent 8B store, NO drain (ordering via sentinel protocol)
__device__ __forceinline__ void store8_nd(unsigned short* p, unsigned long long v) {
  asm volatile("global_store_dwordx2 %0, %1, off sc0 sc1"
               :: "v"(p), "v"(v) : "memory");
}

// coherent 16B store, NO drain (ig epilogue; drained per-thread afterwards)
__device__ __forceinline__ void store16_s(unsigned short* p, int4v v) {
  asm volatile("global_store_dwordx4 %0, %1, off sc0 sc1"
               :: "v"(p), "v"(v) : "memory");
}

__device__ __forceinline__ unsigned poll_s(const unsigned* p) {
  unsigned f;
  asm volatile("global_load_dword %0, %1, off sc0 sc1\n\t"
               "s_waitcnt vmcnt(0)" : "=v"(f) : "v"(p) : "memory");
  return f;
}

__device__ __forceinline__ unsigned pkmax(unsigned a, unsigned b) {
  unsigned d;
  asm("v_pk_max_u16 %0, %1, %2" : "=v"(d) : "v"(a), "v"(b));
  return d;
}
__device__ __forceinline__ bool has_sent(int4v v) {
  unsigned m = pkmax(pkmax((unsigned)v[0], (unsigned)v[1]),
                     pkmax((unsigned)v[2], (unsigned)v[3]));
  return ((m & 0xFFFFu) == 0xFFFFu) || ((m >> 16) == 0xFFFFu);
}

// ---------------------------------------------------------------------------
// Legacy serial ig_gemm (fp32 staging) -- fallback when not fused.
// ---------------------------------------------------------------------------
__global__ __launch_bounds__(256) void ig_gemm(
    const float* __restrict__ x, const float* __restrict__ Wih,
    const float* __restrict__ bias, unsigned short* __restrict__ IG) {
  __shared__ unsigned short As[128 * 40];
  __shared__ unsigned short Bs[128 * 40];
  const int tid = threadIdx.x;
  const int bn = blockIdx.x, bm = blockIdx.y;
  const int lane = tid & 63, w = tid >> 6;
  const int wm = w >> 1, wn = w & 1;
  const int l15 = lane & 15, q = lane >> 4;

  f32x4 acc[4][4] = {};

  for (int kt = 0; kt < 16; ++kt) {
    __syncthreads();
#pragma unroll
    for (int j = 0; j < 4; ++j) {
      int fi = tid + 256 * j;
      int row = fi >> 3, kq = fi & 7;
      float4 v = *(const float4*)(x + (size_t)(bm * 128 + row) * ND + kt * 32 + kq * 4);
      ushort4 s = {f2bf(v.x), f2bf(v.y), f2bf(v.z), f2bf(v.w)};
      *(ushort4*)&As[row * 40 + kq * 4] = s;
    }
#pragma unroll
    for (int j = 0; j < 4; ++j) {
      int fi = tid + 256 * j;
      int row = fi >> 3, kq = fi & 7;
      float4 v = *(const float4*)(Wih + (size_t)(bn * 128 + row) * ND + kt * 32 + kq * 4);
      ushort4 s = {f2bf(v.x), f2bf(v.y), f2bf(v.z), f2bf(v.w)};
      *(ushort4*)&Bs[row * 40 + kq * 4] = s;
    }
    __syncthreads();

    short8 af[4], bf[4];
#pragma unroll
    for (int tm = 0; tm < 4; ++tm)
      af[tm] = *(const short8*)&As[(wm * 64 + tm * 16 + l15) * 40 + q * 8];
#pragma unroll
    for (int tn = 0; tn < 4; ++tn)
      bf[tn] = *(const short8*)&Bs[(wn * 64 + tn * 16 + l15) * 40 + q * 8];
#pragma unroll
    for (int tm = 0; tm < 4; ++tm)
#pragma unroll
      for (int tn = 0; tn < 4; ++tn)
        acc[tm][tn] = __builtin_amdgcn_mfma_f32_16x16x32_bf16(af[tm], bf[tn], acc[tm][tn], 0, 0, 0);
  }

#pragma unroll
  for (int tm = 0; tm < 4; ++tm) {
#pragma unroll
    for (int tn = 0; tn < 4; ++tn) {
      int col = bn * 128 + wn * 64 + tn * 16 + l15;
      float bb = bias[col];
#pragma unroll
      for (int i = 0; i < 4; ++i) {
        int row = bm * 128 + wm * 64 + tm * 16 + q * 4 + i;
        IG[(size_t)row * NG + col] = f2bf(acc[tm][tn][i] + bb);
      }
    }
  }
}

// ---------------------------------------------------------------------------
// One ig tile (fp32 inline staging, R20-proven body) + coalesced Ts
// epilogue + proven store->drain->sync->signal sequence.
// ---------------------------------------------------------------------------
__device__ __forceinline__ void ig_tile(
    const float* __restrict__ x, const float* __restrict__ Wih,
    const float* __restrict__ bias, unsigned short* __restrict__ IG,
    unsigned* __restrict__ qcnt, int bm, int bnn, int qq,
    unsigned short* As, unsigned short* Bs, unsigned short* Ts, int tid) {
  const int lane = tid & 63, w = tid >> 6;
  const int wm = w >> 1, wn = w & 1;
  const int l15 = lane & 15, q = lane >> 4;

  f32x4 acc[4][4] = {};

  for (int kt = 0; kt < 16; ++kt) {
    __syncthreads();
#pragma unroll
    for (int j = 0; j < 4; ++j) {
      int fi = tid + 256 * j;
      int row = fi >> 3, kq = fi & 7;
      float4 v = *(const float4*)(x + (size_t)(bm * 128 + row) * ND + kt * 32 + kq * 4);
      ushort4 s = {f2bf(v.x), f2bf(v.y), f2bf(v.z), f2bf(v.w)};
      *(ushort4*)&As[row * 40 + kq * 4] = s;
    }
#pragma unroll
    for (int j = 0; j < 4; ++j) {
      int fi = tid + 256 * j;
      int row = fi >> 3, kq = fi & 7;
      float4 v = *(const float4*)(Wih + (size_t)(bnn * 128 + row) * ND + kt * 32 + kq * 4);
      ushort4 s = {f2bf(v.x), f2bf(v.y), f2bf(v.z), f2bf(v.w)};
      *(ushort4*)&Bs[row * 40 + kq * 4] = s;
    }
    __syncthreads();

    short8 af[4], bf[4];
#pragma unroll
    for (int tm = 0; tm < 4; ++tm)
      af[tm] = *(const short8*)&As[(wm * 64 + tm * 16 + l15) * 40 + q * 8];
#pragma unroll
    for (int tn = 0; tn < 4; ++tn)
      bf[tn] = *(const short8*)&Bs[(wn * 64 + tn * 16 + l15) * 40 + q * 8];
#pragma unroll
    for (int tm = 0; tm < 4; ++tm)
#pragma unroll
      for (int tn = 0; tn < 4; ++tn)
        acc[tm][tn] = __builtin_amdgcn_mfma_f32_16x16x32_bf16(af[tm], bf[tn], acc[tm][tn], 0, 0, 0);
  }

  // epilogue: acc -> Ts (with bias) -> coalesced sc0sc1 stores
#pragma unroll
  for (int tm = 0; tm < 4; ++tm) {
#pragma unroll
    for (int tn = 0; tn < 4; ++tn) {
      int cl = wn * 64 + tn * 16 + l15;
      float bb = bias[bnn * 128 + cl];
#pragma unroll
      for (int i = 0; i < 4; ++i) {
        int rl = wm * 64 + tm * 16 + q * 4 + i;
        Ts[rl * 128 + cl] = f2bf(acc[tm][tn][i] + bb);
      }
    }
  }
  __syncthreads();
#pragma unroll
  for (int j = 0; j < 8; ++j) {
    int gi = tid + 256 * j;                   // 0..2047
    int row = gi >> 4, c16 = gi & 15;         // 16 granules per 128-col row
    store16_s(IG + (size_t)(bm * 128 + row) * NG + bnn * 128 + c16 * 8,
              *(const int4v*)&Ts[row * 128 + c16 * 8]);
  }
  asm volatile("s_waitcnt vmcnt(0)" ::: "memory");  // my stores at IF$
  __syncthreads();                                   // all threads drained
  if (tid == 0) atomicAdd(qcnt + qq, 1u);            // device-scope signal
}

// ---------------------------------------------------------------------------
// GRU body (R16 verbatim) + optional per-quarter IG wait (qcnt != nullptr).
// ---------------------------------------------------------------------------
template <bool USE_IG>
__device__ __forceinline__ void gru_body(
    const float* __restrict__ x, const float* __restrict__ Wih,
    const float* __restrict__ Whh, const float* __restrict__ bias,
    const float* __restrict__ bn, const unsigned short* __restrict__ IG,
    unsigned short* __restrict__ hbuf, float* __restrict__ hfin,
    const unsigned* __restrict__ qcnt,
    unsigned short* hs, unsigned short* ts, int bid) {
  const int tid = threadIdx.x;
  const int lane = tid & 63;
  const int w = tid >> 6;                  // 0..3
  const int l15 = lane & 15, q = lane >> 4;
  const int g = bid & 7, c = bid >> 3;
  const int col = c * 64 + w * 16 + l15;   // this lane's h column
  const int erow = g * 16 + q * 4;         // C-layout batch row base
  const int mrow = g * 16 + l15;           // A-fragment batch row (!USE_IG)

  short8 bfr[3][16];
#pragma unroll
  for (int gt = 0; gt < 3; ++gt) {
    const float* src = Whh + (size_t)(gt * NH + col) * NH + q * 8;
#pragma unroll
    for (int kk = 0; kk < 16; ++kk) {
      float4 v0 = *(const float4*)(src + kk * 32);
      float4 v1 = *(const float4*)(src + kk * 32 + 4);
      bfr[gt][kk] = pack8(v0, v1);
    }
  }

  float bi_r = 0.f, bi_z = 0.f, bi_n = 0.f;
  if (!USE_IG) {
    bi_r = bias[col];
    bi_z = bias[NH + col];
    bi_n = bias[2 * NH + col];
  }
  const float bnv = bn[col];

  float hreg[4] = {0.f, 0.f, 0.f, 0.f};

  const int frow = tid >> 4;          // 0..15
  const int j2 = tid & 15;
  const int fr7 = frow & 7;
  const size_t rowoff = (size_t)(g * 16 + frow) * NH;
  const int e0 = ((j2) ^ fr7) << 3;
  const int e1 = ((j2 + 16) ^ fr7) << 3;
  const int e2 = ((32 + j2) ^ fr7) << 3;
  const int e3 = ((48 + j2) ^ fr7) << 3;

  const int srow = tid >> 4;
  const int scol = (tid & 15) * 4;
  const size_t cell_off = (size_t)(g * 16 + srow) * NH + c * 64 + scol;

  int4v v[4];
  issue4(hbuf + rowoff + e0, hbuf + rowoff + e1,
         hbuf + rowoff + e2, hbuf + rowoff + e3, v);

  for (int t = 0; t < NT; ++t) {
    unsigned short* hnxt  = hbuf + (size_t)((t + 1) & 3) * HSLOT;
    unsigned short* hsent = hbuf + (size_t)((t + 2) & 3) * HSLOT;
    const unsigned short* hrow = hbuf + (size_t)(t & 3) * HSLOT + rowoff;

    // wait for IG quarter to be produced (fused mode only)
    if (USE_IG && qcnt != nullptr && (t & 127) == 0) {
      if (tid == 0) {
        const unsigned* qp = qcnt + (t >> 7);
        unsigned f = poll_s(qp);
        while (f < 1536u) f = poll_s(qp);
      }
      __syncthreads();
    }

    float igr[4], igz[4], ign[4];
    if (USE_IG) {
#pragma unroll
      for (int i = 0; i < 4; ++i) {
        const size_t base = ((size_t)(erow + i) * NT + t) * NG + col;
        igr[i] = bf2f(IG[base]);
        igz[i] = bf2f(IG[base + NH]);
        ign[i] = bf2f(IG[base + 2 * NH]);
      }
    }

    wait4(v);
    if (t > 0) {
      while (has_sent(v[0])) v[0] = load16_s(hrow + e0);
      while (has_sent(v[1])) v[1] = load16_s(hrow + e1);
      while (has_sent(v[2])) v[2] = load16_s(hrow + e2);
      while (has_sent(v[3])) v[3] = load16_s(hrow + e3);
    }
    *(int4v*)&hs[frow * 512 + (j2 << 3)] = v[0];
    *(int4v*)&hs[frow * 512 + ((j2 + 16) << 3)] = v[1];
    *(int4v*)&hs[frow * 512 + ((32 + j2) << 3)] = v[2];
    *(int4v*)&hs[frow * 512 + ((48 + j2) << 3)] = v[3];
    __syncthreads();  // BAR1: full h_t validated + staged

    if (t + 2 < NT) store8_nd(hsent + cell_off, 0xFFFFFFFFFFFFFFFFull);

    f32x4 ar = {0.f, 0.f, 0.f, 0.f};
    f32x4 az = {0.f, 0.f, 0.f, 0.f};
    f32x4 an = {0.f, 0.f, 0.f, 0.f};
    f32x4 ai = {0.f, 0.f, 0.f, 0.f};
    const int abase = l15 * 512;
    const int ar7 = (l15 & 7) << 3;
#pragma unroll
    for (int kk = 0; kk < 16; ++kk) {
      short8 afk = *(const short8*)&hs[abase + ((kk * 32 + q * 8) ^ ar7)];
      ar = __builtin_amdgcn_mfma_f32_16x16x32_bf16(afk, bfr[0][kk], ar, 0, 0, 0);
      az = __builtin_amdgcn_mfma_f32_16x16x32_bf16(afk, bfr[1][kk], az, 0, 0, 0);
      an = __builtin_amdgcn_mfma_f32_16x16x32_bf16(afk, bfr[2][kk], an, 0, 0, 0);
      if (!USE_IG) {
        const float* xp = x + ((size_t)mrow * NT + t) * ND + kk * 32 + q * 8;
        short8 xa = pack8(*(const float4*)xp, *(const float4*)(xp + 4));
#pragma unroll
        for (int gt = 0; gt < 3; ++gt) {
          const float* wp = Wih + (size_t)(gt * NH + col) * ND + kk * 32 + q * 8;
          short8 wf = pack8(*(const float4*)wp, *(const float4*)(wp + 4));
          if (gt == 0) ar = __builtin_amdgcn_mfma_f32_16x16x32_bf16(xa, wf, ar, 0, 0, 0);
          if (gt == 1) az = __builtin_amdgcn_mfma_f32_16x16x32_bf16(xa, wf, az, 0, 0, 0);
          if (gt == 2) ai = __builtin_amdgcn_mfma_f32_16x16x32_bf16(xa, wf, ai, 0, 0, 0);
        }
      }
    }

    unsigned short sv[4];
#pragma unroll
    for (int i = 0; i < 4; ++i) {
      float xr = USE_IG ? (ar[i] + igr[i]) : (ar[i] + bi_r);
      float xz = USE_IG ? (az[i] + igz[i]) : (az[i] + bi_z);
      float xin = USE_IG ? ign[i] : (ai[i] + bi_n);
      float r = sigmoid_f(xr);
      float z = sigmoid_f(xz);
      float n = tanh_f(xin + r * (an[i] + bnv));
      float hn2 = (1.f - z) * n + z * hreg[i];
      hreg[i] = hn2;
      sv[i] = f2bf(hn2);
      if (t == NT - 1) hfin[(size_t)(erow + i) * NH + col] = hn2;
    }

    if (t != NT - 1) {
#pragma unroll
      for (int i = 0; i < 4; ++i)
        ts[(q * 4 + i) * 64 + w * 16 + l15] = sv[i];
      asm volatile("s_waitcnt vmcnt(0)" ::: "memory");
      __syncthreads();  // BAR2
      store8_nd(hnxt + cell_off,
                *(const unsigned long long*)&ts[srow * 64 + scol]);
      issue4(hnxt + rowoff + e0, hnxt + rowoff + e1,
             hnxt + rowoff + e2, hnxt + rowoff + e3, v);
    }
  }
}

// standalone gru (fallback paths)
template <bool USE_IG>
__global__ __launch_bounds__(256, 1) void gru_rec(
    const float* __restrict__ x, const float* __restrict__ Wih,
    const float* __restrict__ Whh, const float* __restrict__ bias,
    const float* __restrict__ bn, const unsigned short* __restrict__ IG,
    unsigned short* __restrict__ hbuf, float* __restrict__ hfin) {
  __shared__ __align__(16) unsigned short hs[16 * 512];
  __shared__ __align__(16) unsigned short ts[16 * 64];
  gru_body<USE_IG>(x, Wih, Whh, bias, bn, IG, hbuf, hfin, nullptr,
                   hs, ts, blockIdx.x);
}

// ---------------------------------------------------------------------------
// Fused persistent kernel. Phase 1: ALL blocks produce quarter-0 (6 tiles
// each). Phase 2: blocks 0..63 gru; blocks 64..255 produce quarters 1..3.
// ---------------------------------------------------------------------------
__global__ __launch_bounds__(256, 1) void fused_gru_ig(
    const float* __restrict__ x, const float* __restrict__ Wih,
    const float* __restrict__ Whh, const float* __restrict__ bias,
    const float* __restrict__ bn, unsigned short* __restrict__ IG,
    unsigned short* __restrict__ hbuf, float* __restrict__ hfin,
    unsigned* __restrict__ qcnt) {
  __shared__ __align__(16) unsigned short hs[16 * 512];  // gru (16 KB)
  __shared__ __align__(16) unsigned short ts[16 * 64];   // gru (2 KB)
  __shared__ __align__(16) unsigned short As[128 * 40];  // ig (10 KB)
  __shared__ __align__(16) unsigned short Bs[128 * 40];  // ig (10 KB)
  __shared__ __align__(16) unsigned short Ts[128 * 128]; // ig (32 KB)

  const int bid = blockIdx.x;
  const int tid = threadIdx.x;

  // phase 1: quarter-0 tiles, all 256 blocks, 6 tiles each (no waits).
#pragma unroll 1
  for (int k = 0; k < 6; ++k) {
    const int tile = bid + 256 * k;        // 0..1535
    const int bmq = tile / 12, bnn = tile - bmq * 12;
    ig_tile(x, Wih, bias, IG, qcnt, bmq * 4 + 0, bnn, 0, As, Bs, Ts, tid);
  }

  if (bid < 64) {
    gru_body<true>(nullptr, nullptr, Whh, bias, bn, IG, hbuf, hfin, qcnt,
                   hs, ts, bid);
    return;
  }

  // phase 2: quarters 1..3 on the 192 producer blocks.
#pragma unroll 1
  for (int tile = 1536 + (bid - 64); tile < 6144; tile += 192) {
    const int qq = tile / 1536;            // 1..3
    const int r = tile - qq * 1536;
    const int bmq = r / 12, bnn = r - bmq * 12;
    ig_tile(x, Wih, bias, IG, qcnt, bmq * 4 + qq, bnn, qq, As, Bs, Ts, tid);
  }
}

// ---------------------------------------------------------------------------
// out = h_T @ Wlin^T + blin (unchanged)
// ---------------------------------------------------------------------------
__global__ __launch_bounds__(256) void final_linear(
    const float* __restrict__ hfin, const float* __restrict__ Wlin,
    const float* __restrict__ blin, float* __restrict__ out) {
  __shared__ float sh[16 * 516];
  const int tid = threadIdx.x;
  const int b0 = blockIdx.y * 16, o0 = blockIdx.x * 16;

  for (int j = tid; j < 16 * 128; j += 256) {
    int row = j >> 7, kq = j & 127;
    *(float4*)&sh[row * 516 + kq * 4] =
        *(const float4*)(hfin + (size_t)(b0 + row) * NH + kq * 4);
  }
  __syncthreads();

  const int bi = tid & 15, oi = tid >> 4;
  const int o = o0 + oi;
  const float4* wp = (const float4*)(Wlin + (size_t)o * NH);
  float4 a4 = {0.f, 0.f, 0.f, 0.f};
  for (int k4 = 0; k4 < 128; ++k4) {
    float4 wv = wp[k4];
    float4 hv = *(const float4*)&sh[bi * 516 + k4 * 4];
    a4.x += wv.x * hv.x; a4.y += wv.y * hv.y;
    a4.z += wv.z * hv.z; a4.w += wv.w * hv.w;
  }
  float v = a4.x + a4.y + a4.z + a4.w + blin[o];
  int b = b0 + bi;
  if (o < 256) out[b * 256 + o] = v;
  else out[32768 + b * 256 + (o - 256)] = v;
}

// ---------------------------------------------------------------------------
extern "C" void kernel_launch(void* const* d_in, const int* in_sizes, int n_in,
                              void* d_out, int out_size, void* d_ws, size_t ws_size,
                              hipStream_t stream) {
  const float* x    = (const float*)d_in[0];
  const float* Wih  = (const float*)d_in[1];
  const float* Whh  = (const float*)d_in[2];
  const float* bias = (const float*)d_in[3];
  const float* bn   = (const float*)d_in[4];
  const float* Wlin = (const float*)d_in[5];
  const float* blin = (const float*)d_in[6];
  float* out = (float*)d_out;

  char* ws = (char*)d_ws;
  // layout: [h ring 524288][hfin 262144][qcnt 1024][IG 201326592]
  unsigned short* hbuf = (unsigned short*)ws;
  float* hfin          = (float*)(ws + 4 * 131072);
  unsigned* qcnt       = (unsigned*)(ws + 4 * 131072 + 262144);
  unsigned short* IG   = (unsigned short*)(ws + 4 * 131072 + 262144 + 1024);
  const size_t need_min = 4 * 131072 + 262144 + 1024;            // 787456
  const size_t need_ig  = need_min + (size_t)NB * NT * NG * 2;   // ~202 MB
  if (ws_size < need_min) return;

  // h slot0 = h_0 = 0; slots 1..3 = 0xFFFF sentinel; qcnt = 0
  hipMemsetAsync(ws, 0, 131072, stream);
  hipMemsetAsync(ws + 131072, 0xFF, 3 * 131072, stream);
  hipMemsetAsync(ws + 4 * 131072 + 262144, 0, 1024, stream);

  const bool useIG = (ws_size >= need_ig);
  if (useIG) {
    fused_gru_ig<<<256, 256, 0, stream>>>(x, Wih, Whh, bias, bn, IG, hbuf,
                                          hfin, qcnt);
  } else {
    gru_rec<false><<<64, 256, 0, stream>>>(x, Wih, Whh, bias, bn, nullptr, hbuf, hfin);
  }
  final_linear<<<dim3(32, 8), 256, 0, stream>>>(hfin, Wlin, blin, out);
}

// Round 18
// 1869.793 us; speedup vs baseline: 1.0257x; 1.0257x over previous
//
#include <hip/hip_runtime.h>
#include <stdint.h>

// ---------------------------------------------------------------------------
// GRU encoder (B=128,T=512,D=512,H=512,L=256), MI355X gfx950.
//
// R23 = R21 (PASSED 1899us: bf16 pre-convert + fused persistent gru+ig)
//       + R22's quarter-0-first phase structure (PASSED)
//       + single merged cvt launch.
// R22's regression isolated to its inline-fp32 staging (FETCH 438->769MB);
// reverted. Everything protocol-level is byte-identical to passing runs:
//   - gru body = R16 verbatim (sentinel ring, prefetch-as-poll, strided
//     fill, 2 barriers) + per-quarter qcnt wait at t%128==0.
//   - ig tile: bf16 staging (R21 fused body), Ts epilogue, sc0sc1 stores ->
//     per-thread vmcnt(0) -> syncthreads -> tid0 atomicAdd(qcnt+qq,1).
//   - gru polls qcnt[t>>7] >= 1536 (each quarter = 1536 tiles).
//   - phase 1: ALL 256 blocks produce quarter-0 (6 tiles each, no waits);
//     phase 2: blocks 0..63 gru, 64..255 quarters 1..3 (stride 192).
// Deadlock-free: grid=256 <= 256 CUs, 70KB LDS, <=256 VGPR -> 1 block/CU,
// all resident; quarter-0 production unconditional; producers never wait.
// ---------------------------------------------------------------------------

typedef short short8 __attribute__((ext_vector_type(8)));
typedef float f32x4 __attribute__((ext_vector_type(4)));
typedef int int4v __attribute__((ext_vector_type(4)));

#define NB 128
#define NT 512
#define ND 512
#define NH 512
#define NG 1536   // 3H
#define HSLOT (NB * NH)  // shorts per h ring slot (128 KB)

__device__ __forceinline__ unsigned short f2bf(float f) {
  union { float f; unsigned u; } v; v.f = f;
  unsigned r = v.u + 0x7fffu + ((v.u >> 16) & 1u);  // RNE
  return (unsigned short)(r >> 16);
}
__device__ __forceinline__ float bf2f(unsigned short u) {
  union { unsigned u; float f; } v; v.u = ((unsigned)u) << 16; return v.f;
}
__device__ __forceinline__ float sigmoid_f(float x) {
  float e = __builtin_amdgcn_exp2f(-1.4426950408889634f * x);
  return __builtin_amdgcn_rcpf(1.0f + e);
}
__device__ __forceinline__ float tanh_f(float x) {
  float e = __builtin_amdgcn_exp2f(2.8853900817779268f * x);
  return 1.0f - 2.0f * __builtin_amdgcn_rcpf(1.0f + e);
}
__device__ __forceinline__ short8 pack8(float4 a, float4 b) {
  short8 s;
  s[0] = (short)f2bf(a.x); s[1] = (short)f2bf(a.y);
  s[2] = (short)f2bf(a.z); s[3] = (short)f2bf(a.w);
  s[4] = (short)f2bf(b.x); s[5] = (short)f2bf(b.y);
  s[6] = (short)f2bf(b.z); s[7] = (short)f2bf(b.w);
  return s;
}

// issue 4 coherent 16B loads, NO wait (prefetch path)
__device__ __forceinline__ void issue4(const unsigned short* r0,
                                       const unsigned short* r1,
                                       const unsigned short* r2,
                                       const unsigned short* r3,
                                       int4v (&v)[4]) {
  asm volatile(
      "global_load_dwordx4 %0, %4, off sc0 sc1\n\t"
      "global_load_dwordx4 %1, %5, off sc0 sc1\n\t"
      "global_load_dwordx4 %2, %6, off sc0 sc1\n\t"
      "global_load_dwordx4 %3, %7, off sc0 sc1"
      : "=&v"(v[0]), "=&v"(v[1]), "=&v"(v[2]), "=&v"(v[3])
      : "v"(r0), "v"(r1), "v"(r2), "v"(r3) : "memory");
}

// drain all vmem; v passed through so later uses are data-ordered after
// the wait (robust against hoisting, rule #18).
__device__ __forceinline__ void wait4(int4v (&v)[4]) {
  asm volatile("s_waitcnt vmcnt(0)"
               : "+v"(v[0]), "+v"(v[1]), "+v"(v[2]), "+v"(v[3]) :: "memory");
}

__device__ __forceinline__ int4v load16_s(const unsigned short* p) {
  int4v v;
  asm volatile("global_load_dwordx4 %0, %1, off sc0 sc1\n\t"
               "s_waitcnt vmcnt(0)"
               : "=v"(v) : "v"(p) : "memory");
  return v;
}

// coalesced coherent 8B store, NO drain (ordering via sentinel protocol)
__device__ __forceinline__ void store8_nd(unsigned short* p, unsigned long long v) {
  asm volatile("global_store_dwordx2 %0, %1, off sc0 sc1"
               :: "v"(p), "v"(v) : "memory");
}

// coherent 16B store, NO drain (ig epilogue; drained per-thread afterwards)
__device__ __forceinline__ void store16_s(unsigned short* p, int4v v) {
  asm volatile("global_store_dwordx4 %0, %1, off sc0 sc1"
               :: "v"(p), "v"(v) : "memory");
}

__device__ __forceinline__ unsigned poll_s(const unsigned* p) {
  unsigned f;
  asm volatile("global_load_dword %0, %1, off sc0 sc1\n\t"
               "s_waitcnt vmcnt(0)" : "=v"(f) : "v"(p) : "memory");
  return f;
}

__device__ __forceinline__ unsigned pkmax(unsigned a, unsigned b) {
  unsigned d;
  asm("v_pk_max_u16 %0, %1, %2" : "=v"(d) : "v"(a), "v"(b));
  return d;
}
__device__ __forceinline__ bool has_sent(int4v v) {
  unsigned m = pkmax(pkmax((unsigned)v[0], (unsigned)v[1]),
                     pkmax((unsigned)v[2], (unsigned)v[3]));
  return ((m & 0xFFFFu) == 0xFFFFu) || ((m >> 16) == 0xFFFFu);
}

// ---------------------------------------------------------------------------
// Merged fp32 -> bf16 convert for x and Wih (RNE, identical numerics).
// ---------------------------------------------------------------------------
__global__ __launch_bounds__(256) void cvt_both(
    const float* __restrict__ x, unsigned short* __restrict__ xb,
    const float* __restrict__ Wih, unsigned short* __restrict__ wb) {
  const int nx = (NB * NT * ND) / 8;   // 4194304
  const int nw = (NG * ND) / 8;        // 98304
  int i = blockIdx.x * blockDim.x + threadIdx.x;
  const int stride = gridDim.x * blockDim.x;
  for (; i < nx + nw; i += stride) {
    if (i < nx) {
      float4 a = ((const float4*)x)[2 * i];
      float4 b = ((const float4*)x)[2 * i + 1];
      *(short8*)&xb[(size_t)i * 8] = pack8(a, b);
    } else {
      const int j = i - nx;
      float4 a = ((const float4*)Wih)[2 * j];
      float4 b = ((const float4*)Wih)[2 * j + 1];
      *(short8*)&wb[(size_t)j * 8] = pack8(a, b);
    }
  }
}

// ---------------------------------------------------------------------------
// Legacy serial ig_gemm (fp32 staging) -- fallback when !useBF.
// ---------------------------------------------------------------------------
__global__ __launch_bounds__(256) void ig_gemm(
    const float* __restrict__ x, const float* __restrict__ Wih,
    const float* __restrict__ bias, unsigned short* __restrict__ IG) {
  __shared__ unsigned short As[128 * 40];
  __shared__ unsigned short Bs[128 * 40];
  const int tid = threadIdx.x;
  const int bn = blockIdx.x, bm = blockIdx.y;
  const int lane = tid & 63, w = tid >> 6;
  const int wm = w >> 1, wn = w & 1;
  const int l15 = lane & 15, q = lane >> 4;

  f32x4 acc[4][4] = {};

  for (int kt = 0; kt < 16; ++kt) {
    __syncthreads();
#pragma unroll
    for (int j = 0; j < 4; ++j) {
      int fi = tid + 256 * j;
      int row = fi >> 3, kq = fi & 7;
      float4 v = *(const float4*)(x + (size_t)(bm * 128 + row) * ND + kt * 32 + kq * 4);
      ushort4 s = {f2bf(v.x), f2bf(v.y), f2bf(v.z), f2bf(v.w)};
      *(ushort4*)&As[row * 40 + kq * 4] = s;
    }
#pragma unroll
    for (int j = 0; j < 4; ++j) {
      int fi = tid + 256 * j;
      int row = fi >> 3, kq = fi & 7;
      float4 v = *(const float4*)(Wih + (size_t)(bn * 128 + row) * ND + kt * 32 + kq * 4);
      ushort4 s = {f2bf(v.x), f2bf(v.y), f2bf(v.z), f2bf(v.w)};
      *(ushort4*)&Bs[row * 40 + kq * 4] = s;
    }
    __syncthreads();

    short8 af[4], bf[4];
#pragma unroll
    for (int tm = 0; tm < 4; ++tm)
      af[tm] = *(const short8*)&As[(wm * 64 + tm * 16 + l15) * 40 + q * 8];
#pragma unroll
    for (int tn = 0; tn < 4; ++tn)
      bf[tn] = *(const short8*)&Bs[(wn * 64 + tn * 16 + l15) * 40 + q * 8];
#pragma unroll
    for (int tm = 0; tm < 4; ++tm)
#pragma unroll
      for (int tn = 0; tn < 4; ++tn)
        acc[tm][tn] = __builtin_amdgcn_mfma_f32_16x16x32_bf16(af[tm], bf[tn], acc[tm][tn], 0, 0, 0);
  }

#pragma unroll
  for (int tm = 0; tm < 4; ++tm) {
#pragma unroll
    for (int tn = 0; tn < 4; ++tn) {
      int col = bn * 128 + wn * 64 + tn * 16 + l15;
      float bb = bias[col];
#pragma unroll
      for (int i = 0; i < 4; ++i) {
        int row = bm * 128 + wm * 64 + tm * 16 + q * 4 + i;
        IG[(size_t)row * NG + col] = f2bf(acc[tm][tn][i] + bb);
      }
    }
  }
}

// ---------------------------------------------------------------------------
// One ig tile, bf16 inputs (R21 fused body) + Ts epilogue + proven
// store->drain->sync->signal sequence.
// ---------------------------------------------------------------------------
__device__ __forceinline__ void ig_tile_bf16(
    const unsigned short* __restrict__ xb, const unsigned short* __restrict__ wb,
    const float* __restrict__ bias, unsigned short* __restrict__ IG,
    unsigned* __restrict__ qcnt, int bm, int bnn, int qq,
    unsigned short* As, unsigned short* Bs, unsigned short* Ts, int tid) {
  const int lane = tid & 63, w = tid >> 6;
  const int wm = w >> 1, wn = w & 1;
  const int l15 = lane & 15, q = lane >> 4;

  f32x4 acc[4][4] = {};

  for (int kt = 0; kt < 16; ++kt) {
    __syncthreads();
#pragma unroll
    for (int j = 0; j < 2; ++j) {
      int gi = tid + 256 * j;            // 512 granules of 8 elems
      int row = gi >> 2, kq = gi & 3;    // 4 granules per 32-col row
      *(short8*)&As[row * 40 + kq * 8] =
          *(const short8*)(xb + (size_t)(bm * 128 + row) * ND + kt * 32 + kq * 8);
    }
#pragma unroll
    for (int j = 0; j < 2; ++j) {
      int gi = tid + 256 * j;
      int row = gi >> 2, kq = gi & 3;
      *(short8*)&Bs[row * 40 + kq * 8] =
          *(const short8*)(wb + (size_t)(bnn * 128 + row) * ND + kt * 32 + kq * 8);
    }
    __syncthreads();

    short8 af[4], bf[4];
#pragma unroll
    for (int tm = 0; tm < 4; ++tm)
      af[tm] = *(const short8*)&As[(wm * 64 + tm * 16 + l15) * 40 + q * 8];
#pragma unroll
    for (int tn = 0; tn < 4; ++tn)
      bf[tn] = *(const short8*)&Bs[(wn * 64 + tn * 16 + l15) * 40 + q * 8];
#pragma unroll
    for (int tm = 0; tm < 4; ++tm)
#pragma unroll
      for (int tn = 0; tn < 4; ++tn)
        acc[tm][tn] = __builtin_amdgcn_mfma_f32_16x16x32_bf16(af[tm], bf[tn], acc[tm][tn], 0, 0, 0);
  }

  // epilogue: acc -> Ts (with bias) -> coalesced sc0sc1 stores
#pragma unroll
  for (int tm = 0; tm < 4; ++tm) {
#pragma unroll
    for (int tn = 0; tn < 4; ++tn) {
      int cl = wn * 64 + tn * 16 + l15;
      float bb = bias[bnn * 128 + cl];
#pragma unroll
      for (int i = 0; i < 4; ++i) {
        int rl = wm * 64 + tm * 16 + q * 4 + i;
        Ts[rl * 128 + cl] = f2bf(acc[tm][tn][i] + bb);
      }
    }
  }
  __syncthreads();
#pragma unroll
  for (int j = 0; j < 8; ++j) {
    int gi = tid + 256 * j;                   // 0..2047
    int row = gi >> 4, c16 = gi & 15;         // 16 granules per 128-col row
    store16_s(IG + (size_t)(bm * 128 + row) * NG + bnn * 128 + c16 * 8,
              *(const int4v*)&Ts[row * 128 + c16 * 8]);
  }
  asm volatile("s_waitcnt vmcnt(0)" ::: "memory");  // my stores at IF$
  __syncthreads();                                   // all threads drained
  if (tid == 0) atomicAdd(qcnt + qq, 1u);            // device-scope signal
}

// ---------------------------------------------------------------------------
// GRU body (R16 verbatim) + optional per-quarter IG wait (qcnt != nullptr).
// ---------------------------------------------------------------------------
template <bool USE_IG>
__device__ __forceinline__ void gru_body(
    const float* __restrict__ x, const float* __restrict__ Wih,
    const float* __restrict__ Whh, const float* __restrict__ bias,
    const float* __restrict__ bn, const unsigned short* __restrict__ IG,
    unsigned short* __restrict__ hbuf, float* __restrict__ hfin,
    const unsigned* __restrict__ qcnt,
    unsigned short* hs, unsigned short* ts, int bid) {
  const int tid = threadIdx.x;
  const int lane = tid & 63;
  const int w = tid >> 6;                  // 0..3
  const int l15 = lane & 15, q = lane >> 4;
  const int g = bid & 7, c = bid >> 3;
  const int col = c * 64 + w * 16 + l15;   // this lane's h column
  const int erow = g * 16 + q * 4;         // C-layout batch row base
  const int mrow = g * 16 + l15;           // A-fragment batch row (!USE_IG)

  short8 bfr[3][16];
#pragma unroll
  for (int gt = 0; gt < 3; ++gt) {
    const float* src = Whh + (size_t)(gt * NH + col) * NH + q * 8;
#pragma unroll
    for (int kk = 0; kk < 16; ++kk) {
      float4 v0 = *(const float4*)(src + kk * 32);
      float4 v1 = *(const float4*)(src + kk * 32 + 4);
      bfr[gt][kk] = pack8(v0, v1);
    }
  }

  float bi_r = 0.f, bi_z = 0.f, bi_n = 0.f;
  if (!USE_IG) {
    bi_r = bias[col];
    bi_z = bias[NH + col];
    bi_n = bias[2 * NH + col];
  }
  const float bnv = bn[col];

  float hreg[4] = {0.f, 0.f, 0.f, 0.f};

  const int frow = tid >> 4;          // 0..15
  const int j2 = tid & 15;
  const int fr7 = frow & 7;
  const size_t rowoff = (size_t)(g * 16 + frow) * NH;
  const int e0 = ((j2) ^ fr7) << 3;
  const int e1 = ((j2 + 16) ^ fr7) << 3;
  const int e2 = ((32 + j2) ^ fr7) << 3;
  const int e3 = ((48 + j2) ^ fr7) << 3;

  const int srow = tid >> 4;
  const int scol = (tid & 15) * 4;
  const size_t cell_off = (size_t)(g * 16 + srow) * NH + c * 64 + scol;

  int4v v[4];
  issue4(hbuf + rowoff + e0, hbuf + rowoff + e1,
         hbuf + rowoff + e2, hbuf + rowoff + e3, v);

  for (int t = 0; t < NT; ++t) {
    unsigned short* hnxt  = hbuf + (size_t)((t + 1) & 3) * HSLOT;
    unsigned short* hsent = hbuf + (size_t)((t + 2) & 3) * HSLOT;
    const unsigned short* hrow = hbuf + (size_t)(t & 3) * HSLOT + rowoff;

    // wait for IG quarter to be produced (fused mode only)
    if (USE_IG && qcnt != nullptr && (t & 127) == 0) {
      if (tid == 0) {
        const unsigned* qp = qcnt + (t >> 7);
        unsigned f = poll_s(qp);
        while (f < 1536u) f = poll_s(qp);
      }
      __syncthreads();
    }

    float igr[4], igz[4], ign[4];
    if (USE_IG) {
#pragma unroll
      for (int i = 0; i < 4; ++i) {
        const size_t base = ((size_t)(erow + i) * NT + t) * NG + col;
        igr[i] = bf2f(IG[base]);
        igz[i] = bf2f(IG[base + NH]);
        ign[i] = bf2f(IG[base + 2 * NH]);
      }
    }

    wait4(v);
    if (t > 0) {
      while (has_sent(v[0])) v[0] = load16_s(hrow + e0);
      while (has_sent(v[1])) v[1] = load16_s(hrow + e1);
      while (has_sent(v[2])) v[2] = load16_s(hrow + e2);
      while (has_sent(v[3])) v[3] = load16_s(hrow + e3);
    }
    *(int4v*)&hs[frow * 512 + (j2 << 3)] = v[0];
    *(int4v*)&hs[frow * 512 + ((j2 + 16) << 3)] = v[1];
    *(int4v*)&hs[frow * 512 + ((32 + j2) << 3)] = v[2];
    *(int4v*)&hs[frow * 512 + ((48 + j2) << 3)] = v[3];
    __syncthreads();  // BAR1: full h_t validated + staged

    if (t + 2 < NT) store8_nd(hsent + cell_off, 0xFFFFFFFFFFFFFFFFull);

    f32x4 ar = {0.f, 0.f, 0.f, 0.f};
    f32x4 az = {0.f, 0.f, 0.f, 0.f};
    f32x4 an = {0.f, 0.f, 0.f, 0.f};
    f32x4 ai = {0.f, 0.f, 0.f, 0.f};
    const int abase = l15 * 512;
    const int ar7 = (l15 & 7) << 3;
#pragma unroll
    for (int kk = 0; kk < 16; ++kk) {
      short8 afk = *(const short8*)&hs[abase + ((kk * 32 + q * 8) ^ ar7)];
      ar = __builtin_amdgcn_mfma_f32_16x16x32_bf16(afk, bfr[0][kk], ar, 0, 0, 0);
      az = __builtin_amdgcn_mfma_f32_16x16x32_bf16(afk, bfr[1][kk], az, 0, 0, 0);
      an = __builtin_amdgcn_mfma_f32_16x16x32_bf16(afk, bfr[2][kk], an, 0, 0, 0);
      if (!USE_IG) {
        const float* xp = x + ((size_t)mrow * NT + t) * ND + kk * 32 + q * 8;
        short8 xa = pack8(*(const float4*)xp, *(const float4*)(xp + 4));
#pragma unroll
        for (int gt = 0; gt < 3; ++gt) {
          const float* wp = Wih + (size_t)(gt * NH + col) * ND + kk * 32 + q * 8;
          short8 wf = pack8(*(const float4*)wp, *(const float4*)(wp + 4));
          if (gt == 0) ar = __builtin_amdgcn_mfma_f32_16x16x32_bf16(xa, wf, ar, 0, 0, 0);
          if (gt == 1) az = __builtin_amdgcn_mfma_f32_16x16x32_bf16(xa, wf, az, 0, 0, 0);
          if (gt == 2) ai = __builtin_amdgcn_mfma_f32_16x16x32_bf16(xa, wf, ai, 0, 0, 0);
        }
      }
    }

    unsigned short sv[4];
#pragma unroll
    for (int i = 0; i < 4; ++i) {
      float xr = USE_IG ? (ar[i] + igr[i]) : (ar[i] + bi_r);
      float xz = USE_IG ? (az[i] + igz[i]) : (az[i] + bi_z);
      float xin = USE_IG ? ign[i] : (ai[i] + bi_n);
      float r = sigmoid_f(xr);
      float z = sigmoid_f(xz);
      float n = tanh_f(xin + r * (an[i] + bnv));
      float hn2 = (1.f - z) * n + z * hreg[i];
      hreg[i] = hn2;
      sv[i] = f2bf(hn2);
      if (t == NT - 1) hfin[(size_t)(erow + i) * NH + col] = hn2;
    }

    if (t != NT - 1) {
#pragma unroll
      for (int i = 0; i < 4; ++i)
        ts[(q * 4 + i) * 64 + w * 16 + l15] = sv[i];
      asm volatile("s_waitcnt vmcnt(0)" ::: "memory");
      __syncthreads();  // BAR2
      store8_nd(hnxt + cell_off,
                *(const unsigned long long*)&ts[srow * 64 + scol]);
      issue4(hnxt + rowoff + e0, hnxt + rowoff + e1,
             hnxt + rowoff + e2, hnxt + rowoff + e3, v);
    }
  }
}

// standalone gru (fallback paths)
template <bool USE_IG>
__global__ __launch_bounds__(256, 1) void gru_rec(
    const float* __restrict__ x, const float* __restrict__ Wih,
    const float* __restrict__ Whh, const float* __restrict__ bias,
    const float* __restrict__ bn, const unsigned short* __restrict__ IG,
    unsigned short* __restrict__ hbuf, float* __restrict__ hfin) {
  __shared__ __align__(16) unsigned short hs[16 * 512];
  __shared__ __align__(16) unsigned short ts[16 * 64];
  gru_body<USE_IG>(x, Wih, Whh, bias, bn, IG, hbuf, hfin, nullptr,
                   hs, ts, blockIdx.x);
}

// ---------------------------------------------------------------------------
// Fused persistent kernel. Phase 1: ALL 256 blocks produce quarter-0 from
// bf16 inputs (6 tiles each). Phase 2: blocks 0..63 gru; 64..255 quarters
// 1..3.
// ---------------------------------------------------------------------------
__global__ __launch_bounds__(256, 1) void fused_gru_ig(
    const float* __restrict__ Whh, const float* __restrict__ bn,
    const unsigned short* __restrict__ xb, const unsigned short* __restrict__ wb,
    const float* __restrict__ bias, unsigned short* __restrict__ IG,
    unsigned short* __restrict__ hbuf, float* __restrict__ hfin,
    unsigned* __restrict__ qcnt) {
  __shared__ __align__(16) unsigned short hs[16 * 512];  // gru (16 KB)
  __shared__ __align__(16) unsigned short ts[16 * 64];   // gru (2 KB)
  __shared__ __align__(16) unsigned short As[128 * 40];  // ig (10 KB)
  __shared__ __align__(16) unsigned short Bs[128 * 40];  // ig (10 KB)
  __shared__ __align__(16) unsigned short Ts[128 * 128]; // ig (32 KB)

  const int bid = blockIdx.x;
  const int tid = threadIdx.x;

  // phase 1: quarter-0 tiles, all 256 blocks, 6 tiles each (no waits).
#pragma unroll 1
  for (int k = 0; k < 6; ++k) {
    const int tile = bid + 256 * k;        // 0..1535
    const int bmq = tile / 12, bnn = tile - bmq * 12;
    ig_tile_bf16(xb, wb, bias, IG, qcnt, bmq * 4 + 0, bnn, 0, As, Bs, Ts, tid);
  }

  if (bid < 64) {
    gru_body<true>(nullptr, nullptr, Whh, bias, bn, IG, hbuf, hfin, qcnt,
                   hs, ts, bid);
    return;
  }

  // phase 2: quarters 1..3 on the 192 producer blocks.
#pragma unroll 1
  for (int tile = 1536 + (bid - 64); tile < 6144; tile += 192) {
    const int qq = tile / 1536;            // 1..3
    const int r = tile - qq * 1536;
    const int bmq = r / 12, bnn = r - bmq * 12;
    ig_tile_bf16(xb, wb, bias, IG, qcnt, bmq * 4 + qq, bnn, qq, As, Bs, Ts, tid);
  }
}

// ---------------------------------------------------------------------------
// out = h_T @ Wlin^T + blin (unchanged)
// ---------------------------------------------------------------------------
__global__ __launch_bounds__(256) void final_linear(
    const float* __restrict__ hfin, const float* __restrict__ Wlin,
    const float* __restrict__ blin, float* __restrict__ out) {
  __shared__ float sh[16 * 516];
  const int tid = threadIdx.x;
  const int b0 = blockIdx.y * 16, o0 = blockIdx.x * 16;

  for (int j = tid; j < 16 * 128; j += 256) {
    int row = j >> 7, kq = j & 127;
    *(float4*)&sh[row * 516 + kq * 4] =
        *(const float4*)(hfin + (size_t)(b0 + row) * NH + kq * 4);
  }
  __syncthreads();

  const int bi = tid & 15, oi = tid >> 4;
  const int o = o0 + oi;
  const float4* wp = (const float4*)(Wlin + (size_t)o * NH);
  float4 a4 = {0.f, 0.f, 0.f, 0.f};
  for (int k4 = 0; k4 < 128; ++k4) {
    float4 wv = wp[k4];
    float4 hv = *(const float4*)&sh[bi * 516 + k4 * 4];
    a4.x += wv.x * hv.x; a4.y += wv.y * hv.y;
    a4.z += wv.z * hv.z; a4.w += wv.w * hv.w;
  }
  float v = a4.x + a4.y + a4.z + a4.w + blin[o];
  int b = b0 + bi;
  if (o < 256) out[b * 256 + o] = v;
  else out[32768 + b * 256 + (o - 256)] = v;
}

// ---------------------------------------------------------------------------
extern "C" void kernel_launch(void* const* d_in, const int* in_sizes, int n_in,
                              void* d_out, int out_size, void* d_ws, size_t ws_size,
                              hipStream_t stream) {
  const float* x    = (const float*)d_in[0];
  const float* Wih  = (const float*)d_in[1];
  const float* Whh  = (const float*)d_in[2];
  const float* bias = (const float*)d_in[3];
  const float* bn   = (const float*)d_in[4];
  const float* Wlin = (const float*)d_in[5];
  const float* blin = (const float*)d_in[6];
  float* out = (float*)d_out;

  char* ws = (char*)d_ws;
  // layout: [h ring 524288][hfin 262144][qcnt 1024][IG 201326592][xb][wb]
  unsigned short* hbuf = (unsigned short*)ws;
  float* hfin          = (float*)(ws + 4 * 131072);
  unsigned* qcnt       = (unsigned*)(ws + 4 * 131072 + 262144);
  unsigned short* IG   = (unsigned short*)(ws + 4 * 131072 + 262144 + 1024);
  const size_t need_min = 4 * 131072 + 262144 + 1024;            // 787456
  const size_t need_ig  = need_min + (size_t)NB * NT * NG * 2;   // ~202 MB
  const size_t need_bf  = need_ig + 67108864ull + 1572864ull;    // ~271 MB
  unsigned short* xb = (unsigned short*)(ws + need_ig);
  unsigned short* wb = (unsigned short*)(ws + need_ig + 67108864ull);
  if (ws_size < need_min) return;

  // h slot0 = h_0 = 0; slots 1..3 = 0xFFFF sentinel; qcnt = 0
  hipMemsetAsync(ws, 0, 131072, stream);
  hipMemsetAsync(ws + 131072, 0xFF, 3 * 131072, stream);
  hipMemsetAsync(ws + 4 * 131072 + 262144, 0, 1024, stream);

  const bool useIG = (ws_size >= need_ig);
  const bool useBF = (ws_size >= need_bf);
  if (useIG && useBF) {
    cvt_both<<<2048, 256, 0, stream>>>(x, xb, Wih, wb);
    fused_gru_ig<<<256, 256, 0, stream>>>(Whh, bn, xb, wb, bias, IG, hbuf,
                                          hfin, qcnt);
  } else if (useIG) {
    ig_gemm<<<dim3(12, 512), 256, 0, stream>>>(x, Wih, bias, IG);
    gru_rec<true><<<64, 256, 0, stream>>>(x, Wih, Whh, bias, bn, IG, hbuf, hfin);
  } else {
    gru_rec<false><<<64, 256, 0, stream>>>(x, Wih, Whh, bias, bn, nullptr, hbuf, hfin);
  }
  final_linear<<<dim3(32, 8), 256, 0, stream>>>(hfin, Wlin, blin, out);
}